// Round 1
// 1275.837 us; speedup vs baseline: 1.0085x; 1.0085x over previous
//
#include <hip/hip_runtime.h>
#include <hip/hip_bf16.h>
#include <math.h>

#define CCH 128   // C
#define DK  32    // edge feature dim
#define NCLS 10

__device__ __forceinline__ float leaky_f(float v) { return v >= 0.f ? v : 0.01f * v; }

// ---------------- CSR build ----------------
__global__ void k_hist(const int* __restrict__ dst, int* __restrict__ cnt, int E) {
  int e = blockIdx.x * 256 + threadIdx.x;
  if (e < E) atomicAdd(&cnt[dst[e]], 1);
}

// shuffle-based scan: 3 barriers per 1024-chunk instead of ~20
__global__ void k_scan(const int* __restrict__ cnt, int* __restrict__ off,
                       int* __restrict__ cur, int N) {
  __shared__ int wsum[16];
  __shared__ int carry_s;
  int t = threadIdx.x;
  int lane = t & 63, w = t >> 6;
  if (t == 0) carry_s = 0;
  __syncthreads();
  for (int base = 0; base < N; base += 1024) {
    int i = base + t;
    int carry = carry_s;  // value from previous chunk (all threads read pre-barrier-A)
    int v = (i < N) ? cnt[i] : 0;
    int s = v;
    #pragma unroll
    for (int d = 1; d < 64; d <<= 1) {
      int tmp = __shfl_up(s, d);
      if (lane >= d) s += tmp;
    }
    if (lane == 63) wsum[w] = s;
    __syncthreads();  // A: wsum ready, carry reads done
    if (t < 16) {
      int u = wsum[t];
      #pragma unroll
      for (int d = 1; d < 16; d <<= 1) {
        int tmp = __shfl_up(u, d);
        if (t >= d) u += tmp;
      }
      wsum[t] = u;  // inclusive scan of wave sums
      if (t == 15) carry_s = carry + u;
    }
    __syncthreads();  // B: wsum scanned
    int wbase = carry + (w > 0 ? wsum[w - 1] : 0);
    int excl = wbase + s - v;
    if (i < N) { off[i] = excl; cur[i] = excl; }
    __syncthreads();  // C: protect wsum from next chunk's writes
  }
  if (t == 0) off[N] = carry_s;
}

// fill CSR, pre-gathering src node per slot (removes one dependent load in k_agg)
__global__ void k_fill(const int* __restrict__ dst, const int* __restrict__ srcArr,
                       int* __restrict__ cur, int* __restrict__ eid,
                       int* __restrict__ esrc, int E) {
  int e = blockIdx.x * 256 + threadIdx.x;
  if (e < E) {
    int p = atomicAdd(&cur[dst[e]], 1);
    eid[p] = e;
    esrc[p] = srcArr[e];
  }
}

// ---------------- initial embed: h = leaky(x @ lin_W[0:128] + lin_b + lin_W[128+cls]) ----------------
__global__ __launch_bounds__(256) void k_embed(
    const float* __restrict__ x, const float* __restrict__ lin_W,
    const float* __restrict__ lin_b, const int* __restrict__ batch,
    const int* __restrict__ y, float* __restrict__ h, int M) {
  __shared__ float Al[32 * 128];
  __shared__ float Wl[32 * 128];
  int t = threadIdx.x;
  int row0 = blockIdx.x * 32;
  for (int i = t * 4; i < 32 * 128; i += 1024) {
    int r = i >> 7, k = i & 127;
    int gr = row0 + r;
    float4 v = {0.f, 0.f, 0.f, 0.f};
    if (gr < M) v = *(const float4*)&x[(size_t)gr * 128 + k];
    *(float4*)&Al[i] = v;
  }
  int c4 = (t & 31) * 4;
  int rb = (t >> 5) * 4;
  float acc[4][4] = {};
  for (int ks = 0; ks < 128; ks += 32) {
    __syncthreads();
    for (int i = t * 4; i < 32 * 128; i += 1024)
      *(float4*)&Wl[i] = *(const float4*)&lin_W[(size_t)ks * 128 + i];
    __syncthreads();
    for (int k = 0; k < 32; k += 4) {
      float4 a[4];
      #pragma unroll
      for (int r = 0; r < 4; ++r) a[r] = *(float4*)&Al[(rb + r) * 128 + ks + k];
      #pragma unroll
      for (int kk = 0; kk < 4; ++kk) {
        float4 w = *(float4*)&Wl[(k + kk) * 128 + c4];
        #pragma unroll
        for (int r = 0; r < 4; ++r) {
          float av = kk == 0 ? a[r].x : kk == 1 ? a[r].y : kk == 2 ? a[r].z : a[r].w;
          acc[r][0] = fmaf(av, w.x, acc[r][0]);
          acc[r][1] = fmaf(av, w.y, acc[r][1]);
          acc[r][2] = fmaf(av, w.z, acc[r][2]);
          acc[r][3] = fmaf(av, w.w, acc[r][3]);
        }
      }
    }
  }
  #pragma unroll
  for (int r = 0; r < 4; ++r) {
    int gr = row0 + rb + r;
    if (gr < M) {
      int cls = y[batch[gr]];
      const float* wrow = &lin_W[(size_t)(128 + cls) * 128];
      float4 o;
      o.x = leaky_f(acc[r][0] + lin_b[c4 + 0] + wrow[c4 + 0]);
      o.y = leaky_f(acc[r][1] + lin_b[c4 + 1] + wrow[c4 + 1]);
      o.z = leaky_f(acc[r][2] + lin_b[c4 + 2] + wrow[c4 + 2]);
      o.w = leaky_f(acc[r][3] + lin_b[c4 + 3] + wrow[c4 + 3]);
      *(float4*)&h[(size_t)gr * 128 + c4] = o;
    }
  }
}

// ---------------- per-conv node projections: P[n] = [h@Wf_top | h@Wf_mid | h@Ws_top | h@Ws_mid] ----------------
__global__ __launch_bounds__(256) void k_proj(
    const float* __restrict__ h, const float* __restrict__ Wf,
    const float* __restrict__ Ws, float* __restrict__ P, int M) {
  __shared__ float Al[32 * 128];
  __shared__ float Wl[32 * 128];
  int t = threadIdx.x;
  int part = blockIdx.y;  // 0:Af 1:Bf 2:As 3:Bs
  const float* Wsrc = (part < 2 ? Wf : Ws) + (size_t)(part & 1) * (128 * 128);
  int row0 = blockIdx.x * 32;
  for (int i = t * 4; i < 32 * 128; i += 1024) {
    int r = i >> 7, k = i & 127;
    int gr = row0 + r;
    float4 v = {0.f, 0.f, 0.f, 0.f};
    if (gr < M) v = *(const float4*)&h[(size_t)gr * 128 + k];
    *(float4*)&Al[i] = v;
  }
  int c4 = (t & 31) * 4;
  int rb = (t >> 5) * 4;
  float acc[4][4] = {};
  for (int ks = 0; ks < 128; ks += 32) {
    __syncthreads();
    for (int i = t * 4; i < 32 * 128; i += 1024)
      *(float4*)&Wl[i] = *(const float4*)&Wsrc[(size_t)ks * 128 + i];
    __syncthreads();
    for (int k = 0; k < 32; k += 4) {
      float4 a[4];
      #pragma unroll
      for (int r = 0; r < 4; ++r) a[r] = *(float4*)&Al[(rb + r) * 128 + ks + k];
      #pragma unroll
      for (int kk = 0; kk < 4; ++kk) {
        float4 w = *(float4*)&Wl[(k + kk) * 128 + c4];
        #pragma unroll
        for (int r = 0; r < 4; ++r) {
          float av = kk == 0 ? a[r].x : kk == 1 ? a[r].y : kk == 2 ? a[r].z : a[r].w;
          acc[r][0] = fmaf(av, w.x, acc[r][0]);
          acc[r][1] = fmaf(av, w.y, acc[r][1]);
          acc[r][2] = fmaf(av, w.z, acc[r][2]);
          acc[r][3] = fmaf(av, w.w, acc[r][3]);
        }
      }
    }
  }
  #pragma unroll
  for (int r = 0; r < 4; ++r) {
    int gr = row0 + rb + r;
    if (gr < M) {
      float4 o = {acc[r][0], acc[r][1], acc[r][2], acc[r][3]};
      *(float4*)&P[(size_t)gr * 512 + part * 128 + c4] = o;
    }
  }
}

// ---------------- fused aggregation (pull, CSR): hout[n] = hin[n] + sum_e sigmoid(gf)*softplus(gs) ----------------
// __launch_bounds__(256, 2): min 2 waves/EU -> 256-VGPR budget. With the bare
// (256) bound the compiler capped at 64 VGPRs (8 waves/EU target) and
// rematerialized wf[32]/ws[32] as per-edge loads inside the inner loop
// (rocprof: VGPR_Count=44 < the 64 floats these arrays need). Keeping them
// register-resident removes ~64 dynamic ops per edge-wave.
__global__ __launch_bounds__(256, 2) void k_agg(
    const float* __restrict__ hin, const float* __restrict__ P,
    const int* __restrict__ off, const int* __restrict__ eidArr,
    const int* __restrict__ esrcArr, const float* __restrict__ ea,
    const float* __restrict__ Wf, const float* __restrict__ Ws,
    const float* __restrict__ bfv, const float* __restrict__ bsv,
    float* __restrict__ hout, int N, int do_leaky) {
  int lane = threadIdx.x & 63;
  int wave = __builtin_amdgcn_readfirstlane(threadIdx.x >> 6);
  int gw = blockIdx.x * 4 + wave;
  int half = gw & 1;
  int ch = half * 64 + lane;
  float wf[DK], ws[DK];
  #pragma unroll
  for (int k = 0; k < DK; ++k) {
    wf[k] = Wf[(size_t)(256 + k) * 128 + ch];
    ws[k] = Ws[(size_t)(256 + k) * 128 + ch];
  }
  float bf_c = bfv[ch], bs_c = bsv[ch];
  int nstreams = (gridDim.x * 4) >> 1;
  for (int n = gw >> 1; n < N; n += nstreams) {
    int i0 = __builtin_amdgcn_readfirstlane(off[n]);
    int i1 = __builtin_amdgcn_readfirstlane(off[n + 1]);
    float acc = hin[(size_t)n * 128 + ch];
    float gf0 = P[(size_t)n * 512 + ch] + bf_c;        // Af + bf
    float gs0 = P[(size_t)n * 512 + 256 + ch] + bs_c;  // As + bs
    #pragma unroll 2
    for (int i = i0; i < i1; ++i) {
      int e = __builtin_amdgcn_readfirstlane(eidArr[i]);
      int s = __builtin_amdgcn_readfirstlane(esrcArr[i]);
      const float4* ep4 = (const float4*)(ea + (size_t)e * DK);
      float4 ev[DK / 4];
      #pragma unroll
      for (int q = 0; q < DK / 4; ++q) ev[q] = ep4[q];
      float gf = gf0 + P[(size_t)s * 512 + 128 + ch];  // + Bf[src]
      float gs = gs0 + P[(size_t)s * 512 + 384 + ch];  // + Bs[src]
      const float* evf = (const float*)ev;
      #pragma unroll
      for (int k = 0; k < DK; ++k) {
        float ek = evf[k];
        gf = fmaf(ek, wf[k], gf);
        gs = fmaf(ek, ws[k], gs);
      }
      float sg = 1.f / (1.f + __expf(-gf));
      float tt = __expf(-fabsf(gs));
      float sp = fmaxf(gs, 0.f) + __logf(1.f + tt);
      acc = fmaf(sg, sp, acc);
    }
    if (do_leaky) acc = leaky_f(acc);
    hout[(size_t)n * 128 + ch] = acc;
  }
}

// ---------------- per-graph mean pool: partial sums over (G, S) grid ----------------
__device__ __forceinline__ int lbound(const int* a, int n, int key) {
  int lo = 0, hi = n;
  while (lo < hi) { int m = (lo + hi) >> 1; if (a[m] < key) lo = m + 1; else hi = m; }
  return lo;
}

__global__ void k_pool(const float* __restrict__ h, const int* __restrict__ batch,
                       float* __restrict__ pooled, int* __restrict__ gcnt, int N) {
  int g = blockIdx.x;
  int sidx = blockIdx.y, sgrid = gridDim.y;
  int t = threadIdx.x;  // 128 threads = channels
  int lo = lbound(batch, N, g);
  int hi = lbound(batch, N, g + 1);
  int len = hi - lo;
  if (sidx == 0 && t == 0) gcnt[g] = len;
  int per = (len + sgrid - 1) / sgrid;
  int a = lo + sidx * per;
  int b = min(hi, a + per);
  if (a >= b) return;
  float s = 0.f;
  for (int n = a; n < b; ++n) s += h[(size_t)n * 128 + t];
  atomicAdd(&pooled[g * 128 + t], s);
}

// ---------------- head: one-hot folded in as fc1_W row (128 + y[g]) ----------------
__global__ void k_fc(const float* __restrict__ pooled, const int* __restrict__ gcnt,
                     const int* __restrict__ y,
                     const float* __restrict__ W1, const float* __restrict__ b1,
                     const float* __restrict__ W2, const float* __restrict__ b2,
                     float* __restrict__ out) {
  int g = blockIdx.x;
  int j = threadIdx.x;  // 64 threads, only 0..31 compute
  float v = 0.f;
  if (j < 32) {
    int cnt = gcnt[g];
    float dot = 0.f;
    for (int k = 0; k < 128; ++k) dot = fmaf(pooled[g * 128 + k], W1[k * 32 + j], dot);
    float a = b1[j] + (cnt > 0 ? dot / (float)cnt + W1[(128 + y[g]) * 32 + j] : 0.f);
    a = leaky_f(a);
    v = a * W2[j];
  }
  #pragma unroll
  for (int o = 32; o > 0; o >>= 1) v += __shfl_down(v, o);
  if (j == 0) out[g] = 1.f / (1.f + __expf(-(v + b2[0])));
}

extern "C" void kernel_launch(void* const* d_in, const int* in_sizes, int n_in,
                              void* d_out, int out_size, void* d_ws, size_t ws_size,
                              hipStream_t stream) {
  const float* x        = (const float*)d_in[0];
  const int*   y        = (const int*)d_in[1];
  const int*   eidx     = (const int*)d_in[2];
  const float* ea       = (const float*)d_in[3];
  const int*   batch    = (const int*)d_in[4];
  const float* lin_W    = (const float*)d_in[5];
  const float* lin_b    = (const float*)d_in[6];
  const float* c1_Wf    = (const float*)d_in[7];
  const float* c1_bf    = (const float*)d_in[8];
  const float* c1_Ws    = (const float*)d_in[9];
  const float* c1_bs    = (const float*)d_in[10];
  const float* c2_Wf    = (const float*)d_in[11];
  const float* c2_bf    = (const float*)d_in[12];
  const float* c2_Ws    = (const float*)d_in[13];
  const float* c2_bs    = (const float*)d_in[14];
  const float* fc1_W    = (const float*)d_in[15];
  const float* fc1_b    = (const float*)d_in[16];
  const float* fc2_W    = (const float*)d_in[17];
  const float* fc2_b    = (const float*)d_in[18];
  float* out = (float*)d_out;

  const int N = in_sizes[0] / 128;
  const int G = in_sizes[1];
  const int E = in_sizes[2] / 2;
  const int* src = eidx;
  const int* dst = eidx + E;

  // workspace layout (16B aligned chunks)
  char* w = (char*)d_ws;
  float* P  = (float*)w;  w += (size_t)N * 512 * 4;
  float* hA = (float*)w;  w += (size_t)N * 128 * 4;
  float* hB = (float*)w;  w += (size_t)N * 128 * 4;
  float* pooled = (float*)w; w += (size_t)G * 128 * 4;
  int* gcnt = (int*)w; w += ((size_t)G * 4 + 15) & ~(size_t)15;
  int* cnt = (int*)w; w += (size_t)N * 4;
  int* off = (int*)w; w += ((size_t)(N + 1) * 4 + 15) & ~(size_t)15;
  int* eid = (int*)w; w += (size_t)E * 4;
  int* esrc = (int*)w; w += (size_t)E * 4;

  // CSR build
  hipMemsetAsync(cnt, 0, (size_t)N * 4, stream);
  hipMemsetAsync(pooled, 0, (size_t)G * 128 * 4, stream);
  k_hist<<<(E + 255) / 256, 256, 0, stream>>>(dst, cnt, E);
  k_scan<<<1, 1024, 0, stream>>>(cnt, off, cnt /*reuse as cursor*/, N);
  k_fill<<<(E + 255) / 256, 256, 0, stream>>>(dst, src, cnt, eid, esrc, E);

  // embed
  k_embed<<<(N + 31) / 32, 256, 0, stream>>>(x, lin_W, lin_b, batch, y, hA, N);

  // conv1
  k_proj<<<dim3((N + 31) / 32, 4), 256, 0, stream>>>(hA, c1_Wf, c1_Ws, P, N);
  k_agg<<<2048, 256, 0, stream>>>(hA, P, off, eid, esrc, ea, c1_Wf, c1_Ws, c1_bf, c1_bs, hB, N, 1);

  // conv2
  k_proj<<<dim3((N + 31) / 32, 4), 256, 0, stream>>>(hB, c2_Wf, c2_Ws, P, N);
  k_agg<<<2048, 256, 0, stream>>>(hB, P, off, eid, esrc, ea, c2_Wf, c2_Ws, c2_bf, c2_bs, hA, N, 0);

  // pool + head
  k_pool<<<dim3(G, 8), 128, 0, stream>>>(hA, batch, pooled, gcnt, N);
  k_fc<<<G, 64, 0, stream>>>(pooled, gcnt, y, fc1_W, fc1_b, fc2_W, fc2_b, out);
}

// Round 2
// 1275.350 us; speedup vs baseline: 1.0089x; 1.0004x over previous
//
#include <hip/hip_runtime.h>
#include <hip/hip_bf16.h>
#include <math.h>

#define CCH 128   // C
#define DK  32    // edge feature dim
#define NCLS 10

__device__ __forceinline__ float leaky_f(float v) { return v >= 0.f ? v : 0.01f * v; }

// ---------------- CSR build ----------------
__global__ void k_hist(const int* __restrict__ dst, int* __restrict__ cnt, int E) {
  int e = blockIdx.x * 256 + threadIdx.x;
  if (e < E) atomicAdd(&cnt[dst[e]], 1);
}

// shuffle-based scan: 3 barriers per 1024-chunk instead of ~20
__global__ void k_scan(const int* __restrict__ cnt, int* __restrict__ off,
                       int* __restrict__ cur, int N) {
  __shared__ int wsum[16];
  __shared__ int carry_s;
  int t = threadIdx.x;
  int lane = t & 63, w = t >> 6;
  if (t == 0) carry_s = 0;
  __syncthreads();
  for (int base = 0; base < N; base += 1024) {
    int i = base + t;
    int carry = carry_s;  // value from previous chunk (all threads read pre-barrier-A)
    int v = (i < N) ? cnt[i] : 0;
    int s = v;
    #pragma unroll
    for (int d = 1; d < 64; d <<= 1) {
      int tmp = __shfl_up(s, d);
      if (lane >= d) s += tmp;
    }
    if (lane == 63) wsum[w] = s;
    __syncthreads();  // A: wsum ready, carry reads done
    if (t < 16) {
      int u = wsum[t];
      #pragma unroll
      for (int d = 1; d < 16; d <<= 1) {
        int tmp = __shfl_up(u, d);
        if (t >= d) u += tmp;
      }
      wsum[t] = u;  // inclusive scan of wave sums
      if (t == 15) carry_s = carry + u;
    }
    __syncthreads();  // B: wsum scanned
    int wbase = carry + (w > 0 ? wsum[w - 1] : 0);
    int excl = wbase + s - v;
    if (i < N) { off[i] = excl; cur[i] = excl; }
    __syncthreads();  // C: protect wsum from next chunk's writes
  }
  if (t == 0) off[N] = carry_s;
}

// fill CSR, pre-gathering src node per slot (removes one dependent load in k_agg)
__global__ void k_fill(const int* __restrict__ dst, const int* __restrict__ srcArr,
                       int* __restrict__ cur, int* __restrict__ eid,
                       int* __restrict__ esrc, int E) {
  int e = blockIdx.x * 256 + threadIdx.x;
  if (e < E) {
    int p = atomicAdd(&cur[dst[e]], 1);
    eid[p] = e;
    esrc[p] = srcArr[e];
  }
}

// ---------------- initial embed: h = leaky(x @ lin_W[0:128] + lin_b + lin_W[128+cls]) ----------------
__global__ __launch_bounds__(256) void k_embed(
    const float* __restrict__ x, const float* __restrict__ lin_W,
    const float* __restrict__ lin_b, const int* __restrict__ batch,
    const int* __restrict__ y, float* __restrict__ h, int M) {
  __shared__ float Al[32 * 128];
  __shared__ float Wl[32 * 128];
  int t = threadIdx.x;
  int row0 = blockIdx.x * 32;
  for (int i = t * 4; i < 32 * 128; i += 1024) {
    int r = i >> 7, k = i & 127;
    int gr = row0 + r;
    float4 v = {0.f, 0.f, 0.f, 0.f};
    if (gr < M) v = *(const float4*)&x[(size_t)gr * 128 + k];
    *(float4*)&Al[i] = v;
  }
  int c4 = (t & 31) * 4;
  int rb = (t >> 5) * 4;
  float acc[4][4] = {};
  for (int ks = 0; ks < 128; ks += 32) {
    __syncthreads();
    for (int i = t * 4; i < 32 * 128; i += 1024)
      *(float4*)&Wl[i] = *(const float4*)&lin_W[(size_t)ks * 128 + i];
    __syncthreads();
    for (int k = 0; k < 32; k += 4) {
      float4 a[4];
      #pragma unroll
      for (int r = 0; r < 4; ++r) a[r] = *(float4*)&Al[(rb + r) * 128 + ks + k];
      #pragma unroll
      for (int kk = 0; kk < 4; ++kk) {
        float4 w = *(float4*)&Wl[(k + kk) * 128 + c4];
        #pragma unroll
        for (int r = 0; r < 4; ++r) {
          float av = kk == 0 ? a[r].x : kk == 1 ? a[r].y : kk == 2 ? a[r].z : a[r].w;
          acc[r][0] = fmaf(av, w.x, acc[r][0]);
          acc[r][1] = fmaf(av, w.y, acc[r][1]);
          acc[r][2] = fmaf(av, w.z, acc[r][2]);
          acc[r][3] = fmaf(av, w.w, acc[r][3]);
        }
      }
    }
  }
  #pragma unroll
  for (int r = 0; r < 4; ++r) {
    int gr = row0 + rb + r;
    if (gr < M) {
      int cls = y[batch[gr]];
      const float* wrow = &lin_W[(size_t)(128 + cls) * 128];
      float4 o;
      o.x = leaky_f(acc[r][0] + lin_b[c4 + 0] + wrow[c4 + 0]);
      o.y = leaky_f(acc[r][1] + lin_b[c4 + 1] + wrow[c4 + 1]);
      o.z = leaky_f(acc[r][2] + lin_b[c4 + 2] + wrow[c4 + 2]);
      o.w = leaky_f(acc[r][3] + lin_b[c4 + 3] + wrow[c4 + 3]);
      *(float4*)&h[(size_t)gr * 128 + c4] = o;
    }
  }
}

// ---------------- per-conv node projections: P[n] = [h@Wf_top | h@Wf_mid | h@Ws_top | h@Ws_mid] ----------------
__global__ __launch_bounds__(256) void k_proj(
    const float* __restrict__ h, const float* __restrict__ Wf,
    const float* __restrict__ Ws, float* __restrict__ P, int M) {
  __shared__ float Al[32 * 128];
  __shared__ float Wl[32 * 128];
  int t = threadIdx.x;
  int part = blockIdx.y;  // 0:Af 1:Bf 2:As 3:Bs
  const float* Wsrc = (part < 2 ? Wf : Ws) + (size_t)(part & 1) * (128 * 128);
  int row0 = blockIdx.x * 32;
  for (int i = t * 4; i < 32 * 128; i += 1024) {
    int r = i >> 7, k = i & 127;
    int gr = row0 + r;
    float4 v = {0.f, 0.f, 0.f, 0.f};
    if (gr < M) v = *(const float4*)&h[(size_t)gr * 128 + k];
    *(float4*)&Al[i] = v;
  }
  int c4 = (t & 31) * 4;
  int rb = (t >> 5) * 4;
  float acc[4][4] = {};
  for (int ks = 0; ks < 128; ks += 32) {
    __syncthreads();
    for (int i = t * 4; i < 32 * 128; i += 1024)
      *(float4*)&Wl[i] = *(const float4*)&Wsrc[(size_t)ks * 128 + i];
    __syncthreads();
    for (int k = 0; k < 32; k += 4) {
      float4 a[4];
      #pragma unroll
      for (int r = 0; r < 4; ++r) a[r] = *(float4*)&Al[(rb + r) * 128 + ks + k];
      #pragma unroll
      for (int kk = 0; kk < 4; ++kk) {
        float4 w = *(float4*)&Wl[(k + kk) * 128 + c4];
        #pragma unroll
        for (int r = 0; r < 4; ++r) {
          float av = kk == 0 ? a[r].x : kk == 1 ? a[r].y : kk == 2 ? a[r].z : a[r].w;
          acc[r][0] = fmaf(av, w.x, acc[r][0]);
          acc[r][1] = fmaf(av, w.y, acc[r][1]);
          acc[r][2] = fmaf(av, w.z, acc[r][2]);
          acc[r][3] = fmaf(av, w.w, acc[r][3]);
        }
      }
    }
  }
  #pragma unroll
  for (int r = 0; r < 4; ++r) {
    int gr = row0 + rb + r;
    if (gr < M) {
      float4 o = {acc[r][0], acc[r][1], acc[r][2], acc[r][3]};
      *(float4*)&P[(size_t)gr * 512 + part * 128 + c4] = o;
    }
  }
}

// ---------------- fused aggregation (pull, CSR): hout[n] = hin[n] + sum_e sigmoid(gf)*softplus(gs) ----------------
// VGPR story: with bare bounds the compiler keeps only 44 VGPRs and
// REMATERIALIZES wf[32]/ws[32] as per-edge global loads (launch_bounds(256,2)
// alone didn't change this — it's a remat heuristic, not a pressure cap).
// The empty asm on each element redefines the value, making remat illegal:
// the weights must stay register-resident across the edge loop.
// unroll 1 on the edge loop keeps ev[] at 32 VGPRs so total stays ~120
// (4 waves/SIMD) instead of ~160+ (2 waves/SIMD).
__global__ __launch_bounds__(256, 2) void k_agg(
    const float* __restrict__ hin, const float* __restrict__ P,
    const int* __restrict__ off, const int* __restrict__ eidArr,
    const int* __restrict__ esrcArr, const float* __restrict__ ea,
    const float* __restrict__ Wf, const float* __restrict__ Ws,
    const float* __restrict__ bfv, const float* __restrict__ bsv,
    float* __restrict__ hout, int N, int do_leaky) {
  int lane = threadIdx.x & 63;
  int wave = __builtin_amdgcn_readfirstlane(threadIdx.x >> 6);
  int gw = blockIdx.x * 4 + wave;
  int half = gw & 1;
  int ch = half * 64 + lane;
  float wf[DK], ws[DK];
  #pragma unroll
  for (int k = 0; k < DK; ++k) {
    wf[k] = Wf[(size_t)(256 + k) * 128 + ch];
    ws[k] = Ws[(size_t)(256 + k) * 128 + ch];
  }
  // Pin: forces register residency, forbids rematerialization of the loads.
  #pragma unroll
  for (int k = 0; k < DK; ++k) {
    asm volatile("" : "+v"(wf[k]));
    asm volatile("" : "+v"(ws[k]));
  }
  float bf_c = bfv[ch], bs_c = bsv[ch];
  int nstreams = (gridDim.x * 4) >> 1;
  for (int n = gw >> 1; n < N; n += nstreams) {
    int i0 = __builtin_amdgcn_readfirstlane(off[n]);
    int i1 = __builtin_amdgcn_readfirstlane(off[n + 1]);
    float acc = hin[(size_t)n * 128 + ch];
    float gf0 = P[(size_t)n * 512 + ch] + bf_c;        // Af + bf
    float gs0 = P[(size_t)n * 512 + 256 + ch] + bs_c;  // As + bs
    #pragma unroll 1
    for (int i = i0; i < i1; ++i) {
      int e = __builtin_amdgcn_readfirstlane(eidArr[i]);
      int s = __builtin_amdgcn_readfirstlane(esrcArr[i]);
      const float4* ep4 = (const float4*)(ea + (size_t)e * DK);
      float4 ev[DK / 4];
      #pragma unroll
      for (int q = 0; q < DK / 4; ++q) ev[q] = ep4[q];
      float gf = gf0 + P[(size_t)s * 512 + 128 + ch];  // + Bf[src]
      float gs = gs0 + P[(size_t)s * 512 + 384 + ch];  // + Bs[src]
      const float* evf = (const float*)ev;
      #pragma unroll
      for (int k = 0; k < DK; ++k) {
        float ek = evf[k];
        gf = fmaf(ek, wf[k], gf);
        gs = fmaf(ek, ws[k], gs);
      }
      float sg = 1.f / (1.f + __expf(-gf));
      float tt = __expf(-fabsf(gs));
      float sp = fmaxf(gs, 0.f) + __logf(1.f + tt);
      acc = fmaf(sg, sp, acc);
    }
    if (do_leaky) acc = leaky_f(acc);
    hout[(size_t)n * 128 + ch] = acc;
  }
}

// ---------------- per-graph mean pool: partial sums over (G, S) grid ----------------
__device__ __forceinline__ int lbound(const int* a, int n, int key) {
  int lo = 0, hi = n;
  while (lo < hi) { int m = (lo + hi) >> 1; if (a[m] < key) lo = m + 1; else hi = m; }
  return lo;
}

__global__ void k_pool(const float* __restrict__ h, const int* __restrict__ batch,
                       float* __restrict__ pooled, int* __restrict__ gcnt, int N) {
  int g = blockIdx.x;
  int sidx = blockIdx.y, sgrid = gridDim.y;
  int t = threadIdx.x;  // 128 threads = channels
  int lo = lbound(batch, N, g);
  int hi = lbound(batch, N, g + 1);
  int len = hi - lo;
  if (sidx == 0 && t == 0) gcnt[g] = len;
  int per = (len + sgrid - 1) / sgrid;
  int a = lo + sidx * per;
  int b = min(hi, a + per);
  if (a >= b) return;
  float s = 0.f;
  for (int n = a; n < b; ++n) s += h[(size_t)n * 128 + t];
  atomicAdd(&pooled[g * 128 + t], s);
}

// ---------------- head: one-hot folded in as fc1_W row (128 + y[g]) ----------------
__global__ void k_fc(const float* __restrict__ pooled, const int* __restrict__ gcnt,
                     const int* __restrict__ y,
                     const float* __restrict__ W1, const float* __restrict__ b1,
                     const float* __restrict__ W2, const float* __restrict__ b2,
                     float* __restrict__ out) {
  int g = blockIdx.x;
  int j = threadIdx.x;  // 64 threads, only 0..31 compute
  float v = 0.f;
  if (j < 32) {
    int cnt = gcnt[g];
    float dot = 0.f;
    for (int k = 0; k < 128; ++k) dot = fmaf(pooled[g * 128 + k], W1[k * 32 + j], dot);
    float a = b1[j] + (cnt > 0 ? dot / (float)cnt + W1[(128 + y[g]) * 32 + j] : 0.f);
    a = leaky_f(a);
    v = a * W2[j];
  }
  #pragma unroll
  for (int o = 32; o > 0; o >>= 1) v += __shfl_down(v, o);
  if (j == 0) out[g] = 1.f / (1.f + __expf(-(v + b2[0])));
}

extern "C" void kernel_launch(void* const* d_in, const int* in_sizes, int n_in,
                              void* d_out, int out_size, void* d_ws, size_t ws_size,
                              hipStream_t stream) {
  const float* x        = (const float*)d_in[0];
  const int*   y        = (const int*)d_in[1];
  const int*   eidx     = (const int*)d_in[2];
  const float* ea       = (const float*)d_in[3];
  const int*   batch    = (const int*)d_in[4];
  const float* lin_W    = (const float*)d_in[5];
  const float* lin_b    = (const float*)d_in[6];
  const float* c1_Wf    = (const float*)d_in[7];
  const float* c1_bf    = (const float*)d_in[8];
  const float* c1_Ws    = (const float*)d_in[9];
  const float* c1_bs    = (const float*)d_in[10];
  const float* c2_Wf    = (const float*)d_in[11];
  const float* c2_bf    = (const float*)d_in[12];
  const float* c2_Ws    = (const float*)d_in[13];
  const float* c2_bs    = (const float*)d_in[14];
  const float* fc1_W    = (const float*)d_in[15];
  const float* fc1_b    = (const float*)d_in[16];
  const float* fc2_W    = (const float*)d_in[17];
  const float* fc2_b    = (const float*)d_in[18];
  float* out = (float*)d_out;

  const int N = in_sizes[0] / 128;
  const int G = in_sizes[1];
  const int E = in_sizes[2] / 2;
  const int* src = eidx;
  const int* dst = eidx + E;

  // workspace layout (16B aligned chunks)
  char* w = (char*)d_ws;
  float* P  = (float*)w;  w += (size_t)N * 512 * 4;
  float* hA = (float*)w;  w += (size_t)N * 128 * 4;
  float* hB = (float*)w;  w += (size_t)N * 128 * 4;
  float* pooled = (float*)w; w += (size_t)G * 128 * 4;
  int* gcnt = (int*)w; w += ((size_t)G * 4 + 15) & ~(size_t)15;
  int* cnt = (int*)w; w += (size_t)N * 4;
  int* off = (int*)w; w += ((size_t)(N + 1) * 4 + 15) & ~(size_t)15;
  int* eid = (int*)w; w += (size_t)E * 4;
  int* esrc = (int*)w; w += (size_t)E * 4;

  // CSR build
  hipMemsetAsync(cnt, 0, (size_t)N * 4, stream);
  hipMemsetAsync(pooled, 0, (size_t)G * 128 * 4, stream);
  k_hist<<<(E + 255) / 256, 256, 0, stream>>>(dst, cnt, E);
  k_scan<<<1, 1024, 0, stream>>>(cnt, off, cnt /*reuse as cursor*/, N);
  k_fill<<<(E + 255) / 256, 256, 0, stream>>>(dst, src, cnt, eid, esrc, E);

  // embed
  k_embed<<<(N + 31) / 32, 256, 0, stream>>>(x, lin_W, lin_b, batch, y, hA, N);

  // conv1
  k_proj<<<dim3((N + 31) / 32, 4), 256, 0, stream>>>(hA, c1_Wf, c1_Ws, P, N);
  k_agg<<<2048, 256, 0, stream>>>(hA, P, off, eid, esrc, ea, c1_Wf, c1_Ws, c1_bf, c1_bs, hB, N, 1);

  // conv2
  k_proj<<<dim3((N + 31) / 32, 4), 256, 0, stream>>>(hB, c2_Wf, c2_Ws, P, N);
  k_agg<<<2048, 256, 0, stream>>>(hB, P, off, eid, esrc, ea, c2_Wf, c2_Ws, c2_bf, c2_bs, hA, N, 0);

  // pool + head
  k_pool<<<dim3(G, 8), 128, 0, stream>>>(hA, batch, pooled, gcnt, N);
  k_fc<<<G, 64, 0, stream>>>(pooled, gcnt, y, fc1_W, fc1_b, fc2_W, fc2_b, out);
}

// Round 3
// 1207.765 us; speedup vs baseline: 1.0654x; 1.0560x over previous
//
#include <hip/hip_runtime.h>
#include <hip/hip_bf16.h>
#include <math.h>

#define CCH 128   // C
#define DK  32    // edge feature dim
#define NCLS 10

typedef __attribute__((ext_vector_type(2))) float f32x2;

__device__ __forceinline__ float leaky_f(float v) { return v >= 0.f ? v : 0.01f * v; }

// ---------------- CSR build ----------------
__global__ void k_hist(const int* __restrict__ dst, int* __restrict__ cnt, int E) {
  int e = blockIdx.x * 256 + threadIdx.x;
  if (e < E) atomicAdd(&cnt[dst[e]], 1);
}

// shuffle-based scan: 3 barriers per 1024-chunk instead of ~20
__global__ void k_scan(const int* __restrict__ cnt, int* __restrict__ off,
                       int* __restrict__ cur, int N) {
  __shared__ int wsum[16];
  __shared__ int carry_s;
  int t = threadIdx.x;
  int lane = t & 63, w = t >> 6;
  if (t == 0) carry_s = 0;
  __syncthreads();
  for (int base = 0; base < N; base += 1024) {
    int i = base + t;
    int carry = carry_s;  // value from previous chunk (all threads read pre-barrier-A)
    int v = (i < N) ? cnt[i] : 0;
    int s = v;
    #pragma unroll
    for (int d = 1; d < 64; d <<= 1) {
      int tmp = __shfl_up(s, d);
      if (lane >= d) s += tmp;
    }
    if (lane == 63) wsum[w] = s;
    __syncthreads();  // A: wsum ready, carry reads done
    if (t < 16) {
      int u = wsum[t];
      #pragma unroll
      for (int d = 1; d < 16; d <<= 1) {
        int tmp = __shfl_up(u, d);
        if (t >= d) u += tmp;
      }
      wsum[t] = u;  // inclusive scan of wave sums
      if (t == 15) carry_s = carry + u;
    }
    __syncthreads();  // B: wsum scanned
    int wbase = carry + (w > 0 ? wsum[w - 1] : 0);
    int excl = wbase + s - v;
    if (i < N) { off[i] = excl; cur[i] = excl; }
    __syncthreads();  // C: protect wsum from next chunk's writes
  }
  if (t == 0) off[N] = carry_s;
}

// fill CSR, pre-gathering src node per slot (removes one dependent load in k_agg)
__global__ void k_fill(const int* __restrict__ dst, const int* __restrict__ srcArr,
                       int* __restrict__ cur, int* __restrict__ eid,
                       int* __restrict__ esrc, int E) {
  int e = blockIdx.x * 256 + threadIdx.x;
  if (e < E) {
    int p = atomicAdd(&cur[dst[e]], 1);
    eid[p] = e;
    esrc[p] = srcArr[e];
  }
}

// ---------------- initial embed: h = leaky(x @ lin_W[0:128] + lin_b + lin_W[128+cls]) ----------------
__global__ __launch_bounds__(256) void k_embed(
    const float* __restrict__ x, const float* __restrict__ lin_W,
    const float* __restrict__ lin_b, const int* __restrict__ batch,
    const int* __restrict__ y, float* __restrict__ h, int M) {
  __shared__ float Al[32 * 128];
  __shared__ float Wl[32 * 128];
  int t = threadIdx.x;
  int row0 = blockIdx.x * 32;
  for (int i = t * 4; i < 32 * 128; i += 1024) {
    int r = i >> 7, k = i & 127;
    int gr = row0 + r;
    float4 v = {0.f, 0.f, 0.f, 0.f};
    if (gr < M) v = *(const float4*)&x[(size_t)gr * 128 + k];
    *(float4*)&Al[i] = v;
  }
  int c4 = (t & 31) * 4;
  int rb = (t >> 5) * 4;
  float acc[4][4] = {};
  for (int ks = 0; ks < 128; ks += 32) {
    __syncthreads();
    for (int i = t * 4; i < 32 * 128; i += 1024)
      *(float4*)&Wl[i] = *(const float4*)&lin_W[(size_t)ks * 128 + i];
    __syncthreads();
    for (int k = 0; k < 32; k += 4) {
      float4 a[4];
      #pragma unroll
      for (int r = 0; r < 4; ++r) a[r] = *(float4*)&Al[(rb + r) * 128 + ks + k];
      #pragma unroll
      for (int kk = 0; kk < 4; ++kk) {
        float4 w = *(float4*)&Wl[(k + kk) * 128 + c4];
        #pragma unroll
        for (int r = 0; r < 4; ++r) {
          float av = kk == 0 ? a[r].x : kk == 1 ? a[r].y : kk == 2 ? a[r].z : a[r].w;
          acc[r][0] = fmaf(av, w.x, acc[r][0]);
          acc[r][1] = fmaf(av, w.y, acc[r][1]);
          acc[r][2] = fmaf(av, w.z, acc[r][2]);
          acc[r][3] = fmaf(av, w.w, acc[r][3]);
        }
      }
    }
  }
  #pragma unroll
  for (int r = 0; r < 4; ++r) {
    int gr = row0 + rb + r;
    if (gr < M) {
      int cls = y[batch[gr]];
      const float* wrow = &lin_W[(size_t)(128 + cls) * 128];
      float4 o;
      o.x = leaky_f(acc[r][0] + lin_b[c4 + 0] + wrow[c4 + 0]);
      o.y = leaky_f(acc[r][1] + lin_b[c4 + 1] + wrow[c4 + 1]);
      o.z = leaky_f(acc[r][2] + lin_b[c4 + 2] + wrow[c4 + 2]);
      o.w = leaky_f(acc[r][3] + lin_b[c4 + 3] + wrow[c4 + 3]);
      *(float4*)&h[(size_t)gr * 128 + c4] = o;
    }
  }
}

// ---------------- per-conv node projections: P[n] = [h@Wf_top | h@Wf_mid | h@Ws_top | h@Ws_mid] ----------------
__global__ __launch_bounds__(256) void k_proj(
    const float* __restrict__ h, const float* __restrict__ Wf,
    const float* __restrict__ Ws, float* __restrict__ P, int M) {
  __shared__ float Al[32 * 128];
  __shared__ float Wl[32 * 128];
  int t = threadIdx.x;
  int part = blockIdx.y;  // 0:Af 1:Bf 2:As 3:Bs
  const float* Wsrc = (part < 2 ? Wf : Ws) + (size_t)(part & 1) * (128 * 128);
  int row0 = blockIdx.x * 32;
  for (int i = t * 4; i < 32 * 128; i += 1024) {
    int r = i >> 7, k = i & 127;
    int gr = row0 + r;
    float4 v = {0.f, 0.f, 0.f, 0.f};
    if (gr < M) v = *(const float4*)&h[(size_t)gr * 128 + k];
    *(float4*)&Al[i] = v;
  }
  int c4 = (t & 31) * 4;
  int rb = (t >> 5) * 4;
  float acc[4][4] = {};
  for (int ks = 0; ks < 128; ks += 32) {
    __syncthreads();
    for (int i = t * 4; i < 32 * 128; i += 1024)
      *(float4*)&Wl[i] = *(const float4*)&Wsrc[(size_t)ks * 128 + i];
    __syncthreads();
    for (int k = 0; k < 32; k += 4) {
      float4 a[4];
      #pragma unroll
      for (int r = 0; r < 4; ++r) a[r] = *(float4*)&Al[(rb + r) * 128 + ks + k];
      #pragma unroll
      for (int kk = 0; kk < 4; ++kk) {
        float4 w = *(float4*)&Wl[(k + kk) * 128 + c4];
        #pragma unroll
        for (int r = 0; r < 4; ++r) {
          float av = kk == 0 ? a[r].x : kk == 1 ? a[r].y : kk == 2 ? a[r].z : a[r].w;
          acc[r][0] = fmaf(av, w.x, acc[r][0]);
          acc[r][1] = fmaf(av, w.y, acc[r][1]);
          acc[r][2] = fmaf(av, w.z, acc[r][2]);
          acc[r][3] = fmaf(av, w.w, acc[r][3]);
        }
      }
    }
  }
  #pragma unroll
  for (int r = 0; r < 4; ++r) {
    int gr = row0 + rb + r;
    if (gr < M) {
      float4 o = {acc[r][0], acc[r][1], acc[r][2], acc[r][3]};
      *(float4*)&P[(size_t)gr * 512 + part * 128 + c4] = o;
    }
  }
}

// ---------------- fused aggregation (pull, CSR) ----------------
// R2 restructure: ONE wave per node, 2 channels/lane as f32x2 (v_pk_fma_f32).
// vs the old 2-half-wave layout this halves edge-wave iterations (1.6M -> 0.8M):
// ev/eid/esrc loads, loop control, and transcendental setup are no longer
// duplicated across two waves, and the 128 scalar FMAs/edge (2 waves x 64)
// become 64 pk-FMAs in one wave.
__global__ __launch_bounds__(256, 2) void k_agg(
    const float* __restrict__ hin, const float* __restrict__ P,
    const int* __restrict__ off, const int* __restrict__ eidArr,
    const int* __restrict__ esrcArr, const float* __restrict__ ea,
    const float* __restrict__ Wf, const float* __restrict__ Ws,
    const float* __restrict__ bfv, const float* __restrict__ bsv,
    float* __restrict__ hout, int N, int do_leaky) {
  int lane = threadIdx.x & 63;
  int wave = __builtin_amdgcn_readfirstlane(threadIdx.x >> 6);
  int gw = blockIdx.x * 4 + wave;
  int c2 = lane * 2;  // this lane owns channels c2, c2+1
  f32x2 wf[DK], ws[DK];
  #pragma unroll
  for (int k = 0; k < DK; ++k) {
    wf[k] = *(const f32x2*)&Wf[(size_t)(256 + k) * 128 + c2];
    ws[k] = *(const f32x2*)&Ws[(size_t)(256 + k) * 128 + c2];
  }
  // Pin: forbid rematerialization of the weight loads inside the edge loop.
  #pragma unroll
  for (int k = 0; k < DK; ++k) {
    asm volatile("" : "+v"(wf[k]));
    asm volatile("" : "+v"(ws[k]));
  }
  f32x2 bf2 = *(const f32x2*)&bfv[c2];
  f32x2 bs2 = *(const f32x2*)&bsv[c2];
  int nstreams = gridDim.x * 4;
  for (int n = gw; n < N; n += nstreams) {
    int i0 = __builtin_amdgcn_readfirstlane(off[n]);
    int i1 = __builtin_amdgcn_readfirstlane(off[n + 1]);
    f32x2 acc = *(const f32x2*)&hin[(size_t)n * 128 + c2];
    f32x2 gf0 = *(const f32x2*)&P[(size_t)n * 512 + c2] + bf2;        // Af + bf
    f32x2 gs0 = *(const f32x2*)&P[(size_t)n * 512 + 256 + c2] + bs2;  // As + bs
    #pragma unroll 1
    for (int i = i0; i < i1; ++i) {
      int e = __builtin_amdgcn_readfirstlane(eidArr[i]);
      int s = __builtin_amdgcn_readfirstlane(esrcArr[i]);
      const float4* ep4 = (const float4*)(ea + (size_t)e * DK);
      float4 ev[DK / 4];
      #pragma unroll
      for (int q = 0; q < DK / 4; ++q) ev[q] = ep4[q];
      f32x2 gf = gf0 + *(const f32x2*)&P[(size_t)s * 512 + 128 + c2];  // + Bf[src]
      f32x2 gs = gs0 + *(const f32x2*)&P[(size_t)s * 512 + 384 + c2];  // + Bs[src]
      const float* evf = (const float*)ev;
      #pragma unroll
      for (int k = 0; k < DK; ++k) {
        float ek = evf[k];
        f32x2 ek2 = {ek, ek};
        gf += ek2 * wf[k];
        gs += ek2 * ws[k];
      }
      float sgx = 1.f / (1.f + __expf(-gf.x));
      float sgy = 1.f / (1.f + __expf(-gf.y));
      float spx = fmaxf(gs.x, 0.f) + __logf(1.f + __expf(-fabsf(gs.x)));
      float spy = fmaxf(gs.y, 0.f) + __logf(1.f + __expf(-fabsf(gs.y)));
      acc.x = fmaf(sgx, spx, acc.x);
      acc.y = fmaf(sgy, spy, acc.y);
    }
    if (do_leaky) { acc.x = leaky_f(acc.x); acc.y = leaky_f(acc.y); }
    *(f32x2*)&hout[(size_t)n * 128 + c2] = acc;
  }
}

// ---------------- per-graph mean pool: partial sums over (G, S) grid ----------------
__device__ __forceinline__ int lbound(const int* a, int n, int key) {
  int lo = 0, hi = n;
  while (lo < hi) { int m = (lo + hi) >> 1; if (a[m] < key) lo = m + 1; else hi = m; }
  return lo;
}

__global__ void k_pool(const float* __restrict__ h, const int* __restrict__ batch,
                       float* __restrict__ pooled, int* __restrict__ gcnt, int N) {
  int g = blockIdx.x;
  int sidx = blockIdx.y, sgrid = gridDim.y;
  int t = threadIdx.x;  // 128 threads = channels
  int lo = lbound(batch, N, g);
  int hi = lbound(batch, N, g + 1);
  int len = hi - lo;
  if (sidx == 0 && t == 0) gcnt[g] = len;
  int per = (len + sgrid - 1) / sgrid;
  int a = lo + sidx * per;
  int b = min(hi, a + per);
  if (a >= b) return;
  float s = 0.f;
  for (int n = a; n < b; ++n) s += h[(size_t)n * 128 + t];
  atomicAdd(&pooled[g * 128 + t], s);
}

// ---------------- head: one-hot folded in as fc1_W row (128 + y[g]) ----------------
__global__ void k_fc(const float* __restrict__ pooled, const int* __restrict__ gcnt,
                     const int* __restrict__ y,
                     const float* __restrict__ W1, const float* __restrict__ b1,
                     const float* __restrict__ W2, const float* __restrict__ b2,
                     float* __restrict__ out) {
  int g = blockIdx.x;
  int j = threadIdx.x;  // 64 threads, only 0..31 compute
  float v = 0.f;
  if (j < 32) {
    int cnt = gcnt[g];
    float dot = 0.f;
    for (int k = 0; k < 128; ++k) dot = fmaf(pooled[g * 128 + k], W1[k * 32 + j], dot);
    float a = b1[j] + (cnt > 0 ? dot / (float)cnt + W1[(128 + y[g]) * 32 + j] : 0.f);
    a = leaky_f(a);
    v = a * W2[j];
  }
  #pragma unroll
  for (int o = 32; o > 0; o >>= 1) v += __shfl_down(v, o);
  if (j == 0) out[g] = 1.f / (1.f + __expf(-(v + b2[0])));
}

extern "C" void kernel_launch(void* const* d_in, const int* in_sizes, int n_in,
                              void* d_out, int out_size, void* d_ws, size_t ws_size,
                              hipStream_t stream) {
  const float* x        = (const float*)d_in[0];
  const int*   y        = (const int*)d_in[1];
  const int*   eidx     = (const int*)d_in[2];
  const float* ea       = (const float*)d_in[3];
  const int*   batch    = (const int*)d_in[4];
  const float* lin_W    = (const float*)d_in[5];
  const float* lin_b    = (const float*)d_in[6];
  const float* c1_Wf    = (const float*)d_in[7];
  const float* c1_bf    = (const float*)d_in[8];
  const float* c1_Ws    = (const float*)d_in[9];
  const float* c1_bs    = (const float*)d_in[10];
  const float* c2_Wf    = (const float*)d_in[11];
  const float* c2_bf    = (const float*)d_in[12];
  const float* c2_Ws    = (const float*)d_in[13];
  const float* c2_bs    = (const float*)d_in[14];
  const float* fc1_W    = (const float*)d_in[15];
  const float* fc1_b    = (const float*)d_in[16];
  const float* fc2_W    = (const float*)d_in[17];
  const float* fc2_b    = (const float*)d_in[18];
  float* out = (float*)d_out;

  const int N = in_sizes[0] / 128;
  const int G = in_sizes[1];
  const int E = in_sizes[2] / 2;
  const int* src = eidx;
  const int* dst = eidx + E;

  // workspace layout (16B aligned chunks)
  char* w = (char*)d_ws;
  float* P  = (float*)w;  w += (size_t)N * 512 * 4;
  float* hA = (float*)w;  w += (size_t)N * 128 * 4;
  float* hB = (float*)w;  w += (size_t)N * 128 * 4;
  float* pooled = (float*)w; w += (size_t)G * 128 * 4;
  int* gcnt = (int*)w; w += ((size_t)G * 4 + 15) & ~(size_t)15;
  int* cnt = (int*)w; w += (size_t)N * 4;
  int* off = (int*)w; w += ((size_t)(N + 1) * 4 + 15) & ~(size_t)15;
  int* eid = (int*)w; w += (size_t)E * 4;
  int* esrc = (int*)w; w += (size_t)E * 4;

  // CSR build
  hipMemsetAsync(cnt, 0, (size_t)N * 4, stream);
  hipMemsetAsync(pooled, 0, (size_t)G * 128 * 4, stream);
  k_hist<<<(E + 255) / 256, 256, 0, stream>>>(dst, cnt, E);
  k_scan<<<1, 1024, 0, stream>>>(cnt, off, cnt /*reuse as cursor*/, N);
  k_fill<<<(E + 255) / 256, 256, 0, stream>>>(dst, src, cnt, eid, esrc, E);

  // embed
  k_embed<<<(N + 31) / 32, 256, 0, stream>>>(x, lin_W, lin_b, batch, y, hA, N);

  // conv1
  k_proj<<<dim3((N + 31) / 32, 4), 256, 0, stream>>>(hA, c1_Wf, c1_Ws, P, N);
  k_agg<<<2048, 256, 0, stream>>>(hA, P, off, eid, esrc, ea, c1_Wf, c1_Ws, c1_bf, c1_bs, hB, N, 1);

  // conv2
  k_proj<<<dim3((N + 31) / 32, 4), 256, 0, stream>>>(hB, c2_Wf, c2_Ws, P, N);
  k_agg<<<2048, 256, 0, stream>>>(hB, P, off, eid, esrc, ea, c2_Wf, c2_Ws, c2_bf, c2_bs, hA, N, 0);

  // pool + head
  k_pool<<<dim3(G, 8), 128, 0, stream>>>(hA, batch, pooled, gcnt, N);
  k_fc<<<G, 64, 0, stream>>>(pooled, gcnt, y, fc1_W, fc1_b, fc2_W, fc2_b, out);
}